// Round 8
// baseline (157.031 us; speedup 1.0000x reference)
//
#include <hip/hip_runtime.h>
#include <hip/hip_bf16.h>

typedef __bf16 bf16_t;
typedef bf16_t bf16x4 __attribute__((ext_vector_type(4)));
typedef bf16_t bf16x8 __attribute__((ext_vector_type(8)));
typedef float  f32x4  __attribute__((ext_vector_type(4)));

constexpr int M_TOT = 65536;   // B*S
constexpr int N_TOT = 512;     // E
constexpr int K_TOT = 512;     // E
constexpr int BM = 128, BN = 128, BK = 64;
constexpr int NT = K_TOT / BK; // 8 K-tiles

// W (f32 [N][K]) -> plain bf16 [N][K]. B is consumed global->reg (L2-resident,
// 512 KB); no LDS staging for B => no swizzle image needed.
__global__ __launch_bounds__(256)
void convert_W(const float* __restrict__ W, bf16_t* __restrict__ Wb)
{
    const int g = blockIdx.x * 256 + threadIdx.x;   // 32768 chunks of 8 elems
    const float4* src = reinterpret_cast<const float4*>(W + (size_t)g * 8);
    float4 v0 = src[0], v1 = src[1];
    bf16x8 b;
    b[0] = (bf16_t)v0.x; b[1] = (bf16_t)v0.y; b[2] = (bf16_t)v0.z; b[3] = (bf16_t)v0.w;
    b[4] = (bf16_t)v1.x; b[5] = (bf16_t)v1.y; b[6] = (bf16_t)v1.z; b[7] = (bf16_t)v1.w;
    *reinterpret_cast<bf16x8*>(Wb + (size_t)g * 8) = b;
}

// out[m,n] = sum_k cos(x[m,k] + phi[k%8]) * W[n,k] + bias[n]
// Structure (R8): A double-buffered in LDS (32 KB), B fragments read DIRECTLY
// from L2 (Wb bf16, 512 KB, L2-resident) into registers -- no B LDS, no
// gload_lds, no vmcnt at barriers. ONE lgkm-only barrier per K-step:
//   step t: bfr0 loads -> cos(x(t+1))->As[cur^1] -> bfr1 loads -> issue x(t+2)
//           -> af0+MFMA -> af1+MFMA -> lgkmcnt(0); s_barrier
// R3 lesson: never over-ask occupancy (spill tripwire: FETCH/VGPR anomalies).
template<bool USE_WS>
__global__ __launch_bounds__(256, 3)
void qattn_fused_gemm(const float* __restrict__ x,
                      const float* __restrict__ phi,
                      const float* __restrict__ W,
                      const bf16_t* __restrict__ Wb,
                      const float* __restrict__ bias,
                      float* __restrict__ out)
{
    __shared__ bf16_t As[2][BM][BK];   // 32 KB, XOR-swizzled, double-buffered

    const int tid  = threadIdx.x;
    const int lane = tid & 63;
    const int wave = tid >> 6;

    // XCD-bijective swizzle: the 4 blocks sharing an x-panel on one XCD's L2.
    const int xcd = blockIdx.x & 7;
    const int idx = blockIdx.x >> 3;
    const int wid = xcd * 256 + idx;
    const int bm  = (wid >> 2) * BM;
    const int bn  = (wid & 3)  * BN;

    // A staging: 16 rows x 16 float4 per pass, 8 passes (coalesced 256B/16 lanes)
    const int srow = tid >> 4;
    const int scol = (tid & 15) * 4;
    const int pbase = scol & 4;
    const float p0 = phi[pbase + 0];
    const float p1 = phi[pbase + 1];
    const float p2 = phi[pbase + 2];
    const float p3 = phi[pbase + 3];

    const int wm   = (wave >> 1) * 64;
    const int wn   = (wave & 1) * 64;
    const int frow = lane & 15;
    const int fk   = (lane >> 4) * 8;

    // this lane's B rows: bn + wn + nj*16 + frow (nj static), cols k0+kk*32+fk
    const bf16_t* wbase = Wb + (size_t)(bn + wn + frow) * K_TOT;
    const float*  wfbase = W + (size_t)(bn + wn + frow) * K_TOT;

    f32x4  acc[4][4] = {};
    float4 pa[8];

    const float* xb = x + (size_t)bm * K_TOT;

    // ================= prologue =================
    #pragma unroll
    for (int p = 0; p < 8; ++p)
        pa[p] = *reinterpret_cast<const float4*>(
            xb + (size_t)(srow + p * 16) * K_TOT + scol);
    #pragma unroll
    for (int p = 0; p < 8; ++p) {
        const int row = srow + p * 16;
        const int csw = scol ^ ((row & 7) << 3);
        bf16x4 a;
        a[0] = (bf16_t)__cosf(pa[p].x + p0);
        a[1] = (bf16_t)__cosf(pa[p].y + p1);
        a[2] = (bf16_t)__cosf(pa[p].z + p2);
        a[3] = (bf16_t)__cosf(pa[p].w + p3);
        *reinterpret_cast<bf16x4*>(&As[0][row][csw]) = a;
    }
    // issue x(1); stays in flight across the barrier
    #pragma unroll
    for (int p = 0; p < 8; ++p)
        pa[p] = *reinterpret_cast<const float4*>(
            xb + (size_t)(srow + p * 16) * K_TOT + BK + scol);
    asm volatile("s_waitcnt lgkmcnt(0)\n\ts_barrier" ::: "memory");

    // ================= main loop (fully unrolled) =================
    #pragma unroll
    for (int t = 0; t < NT; ++t) {
        const int cur = t & 1;
        const int k0  = t * BK;

        // ---- bfr0: B frags kk=0, straight from L2 (cos phase covers latency) ----
        bf16x8 bfr0[4];
        if constexpr (USE_WS) {
            #pragma unroll
            for (int nj = 0; nj < 4; ++nj)
                bfr0[nj] = *reinterpret_cast<const bf16x8*>(
                    wbase + (size_t)nj * 16 * K_TOT + k0 + fk);
        } else {
            #pragma unroll
            for (int nj = 0; nj < 4; ++nj) {
                const float* s = wfbase + (size_t)nj * 16 * K_TOT + k0 + fk;
                float4 u0 = *reinterpret_cast<const float4*>(s);
                float4 u1 = *reinterpret_cast<const float4*>(s + 4);
                bfr0[nj][0] = (bf16_t)u0.x; bfr0[nj][1] = (bf16_t)u0.y;
                bfr0[nj][2] = (bf16_t)u0.z; bfr0[nj][3] = (bf16_t)u0.w;
                bfr0[nj][4] = (bf16_t)u1.x; bfr0[nj][5] = (bf16_t)u1.y;
                bfr0[nj][6] = (bf16_t)u1.z; bfr0[nj][7] = (bf16_t)u1.w;
            }
        }

        // ---- cos(x(t+1)) -> As[cur^1] ----
        if (t < NT - 1) {
            #pragma unroll
            for (int p = 0; p < 8; ++p) {
                const int row = srow + p * 16;
                const int csw = scol ^ ((row & 7) << 3);
                bf16x4 a;
                a[0] = (bf16_t)__cosf(pa[p].x + p0);
                a[1] = (bf16_t)__cosf(pa[p].y + p1);
                a[2] = (bf16_t)__cosf(pa[p].z + p2);
                a[3] = (bf16_t)__cosf(pa[p].w + p3);
                *reinterpret_cast<bf16x4*>(&As[cur ^ 1][row][csw]) = a;
            }
        }

        // ---- bfr1: B frags kk=1 ----
        bf16x8 bfr1[4];
        if constexpr (USE_WS) {
            #pragma unroll
            for (int nj = 0; nj < 4; ++nj)
                bfr1[nj] = *reinterpret_cast<const bf16x8*>(
                    wbase + (size_t)nj * 16 * K_TOT + k0 + 32 + fk);
        } else {
            #pragma unroll
            for (int nj = 0; nj < 4; ++nj) {
                const float* s = wfbase + (size_t)nj * 16 * K_TOT + k0 + 32 + fk;
                float4 u0 = *reinterpret_cast<const float4*>(s);
                float4 u1 = *reinterpret_cast<const float4*>(s + 4);
                bfr1[nj][0] = (bf16_t)u0.x; bfr1[nj][1] = (bf16_t)u0.y;
                bfr1[nj][2] = (bf16_t)u0.z; bfr1[nj][3] = (bf16_t)u0.w;
                bfr1[nj][4] = (bf16_t)u1.x; bfr1[nj][5] = (bf16_t)u1.y;
                bfr1[nj][6] = (bf16_t)u1.z; bfr1[nj][7] = (bf16_t)u1.w;
            }
        }

        // ---- issue x(t+2) (pa regs free after cos consumed them) ----
        if (t < NT - 2) {
            #pragma unroll
            for (int p = 0; p < 8; ++p)
                pa[p] = *reinterpret_cast<const float4*>(
                    xb + (size_t)(srow + p * 16) * K_TOT + (t + 2) * BK + scol);
        }

        // ---- kk=0: af ds_read + 16 MFMA ----
        {
            bf16x8 af[4];
            #pragma unroll
            for (int mi = 0; mi < 4; ++mi) {
                const int r = wm + mi * 16 + frow;
                af[mi] = *reinterpret_cast<bf16x8*>(&As[cur][r][fk ^ ((r & 7) << 3)]);
            }
            __builtin_amdgcn_s_setprio(1);
            #pragma unroll
            for (int mi = 0; mi < 4; ++mi)
                #pragma unroll
                for (int nj = 0; nj < 4; ++nj)
                    acc[mi][nj] = __builtin_amdgcn_mfma_f32_16x16x32_bf16(
                        af[mi], bfr0[nj], acc[mi][nj], 0, 0, 0);
            __builtin_amdgcn_s_setprio(0);
        }

        // ---- kk=1: af ds_read + 16 MFMA ----
        {
            bf16x8 af[4];
            #pragma unroll
            for (int mi = 0; mi < 4; ++mi) {
                const int r = wm + mi * 16 + frow;
                af[mi] = *reinterpret_cast<bf16x8*>(&As[cur][r][(32 + fk) ^ ((r & 7) << 3)]);
            }
            __builtin_amdgcn_s_setprio(1);
            #pragma unroll
            for (int mi = 0; mi < 4; ++mi)
                #pragma unroll
                for (int nj = 0; nj < 4; ++nj)
                    acc[mi][nj] = __builtin_amdgcn_mfma_f32_16x16x32_bf16(
                        af[mi], bfr1[nj], acc[mi][nj], 0, 0, 0);
            __builtin_amdgcn_s_setprio(0);
        }

        // ---- single lgkm-only barrier: my As[cur] reads drained, my
        //      As[cur^1] writes visible; no vmcnt coupling at all ----
        if (t < NT - 1)
            asm volatile("s_waitcnt lgkmcnt(0)\n\ts_barrier" ::: "memory");
    }

    // ---- epilogue: C/D map col=lane&15, row=(lane>>4)*4+i ----
    #pragma unroll
    for (int nj = 0; nj < 4; ++nj) {
        const int c  = bn + wn + nj * 16 + frow;
        const float bv = bias[c];
        #pragma unroll
        for (int mi = 0; mi < 4; ++mi) {
            const int r0 = bm + wm + mi * 16 + (lane >> 4) * 4;
            #pragma unroll
            for (int i = 0; i < 4; ++i)
                out[(size_t)(r0 + i) * N_TOT + c] = acc[mi][nj][i] + bv;
        }
    }
}

extern "C" void kernel_launch(void* const* d_in, const int* in_sizes, int n_in,
                              void* d_out, int out_size, void* d_ws, size_t ws_size,
                              hipStream_t stream) {
    const float* x    = (const float*)d_in[0];
    const float* phi  = (const float*)d_in[1];
    const float* W    = (const float*)d_in[2];
    const float* bias = (const float*)d_in[3];
    float* out = (float*)d_out;

    const int grid = (M_TOT / BM) * (N_TOT / BN);   // 2048
    const size_t ws_need = (size_t)N_TOT * K_TOT * sizeof(bf16_t);  // 512 KB

    if (ws_size >= ws_need) {
        bf16_t* Wb = (bf16_t*)d_ws;
        convert_W<<<(N_TOT * K_TOT / 8) / 256, 256, 0, stream>>>(W, Wb);
        qattn_fused_gemm<true><<<grid, 256, 0, stream>>>(x, phi, W, Wb, bias, out);
    } else {
        qattn_fused_gemm<false><<<grid, 256, 0, stream>>>(x, phi, W, nullptr, bias, out);
    }
}

// Round 9
// 95.138 us; speedup vs baseline: 1.6506x; 1.6506x over previous
//
#include <hip/hip_runtime.h>
#include <hip/hip_bf16.h>

typedef __bf16 bf16_t;
typedef bf16_t bf16x4 __attribute__((ext_vector_type(4)));
typedef bf16_t bf16x8 __attribute__((ext_vector_type(8)));
typedef float  f32x4  __attribute__((ext_vector_type(4)));

constexpr int M_TOT = 65536;   // B*S
constexpr int N_TOT = 512;     // E
constexpr int K_TOT = 512;     // E
constexpr int BM = 128, BN = 128, BK = 64;
constexpr int NT = K_TOT / BK; // 8 K-tiles

__device__ inline void gload_lds16(const void* g, void* l) {
    __builtin_amdgcn_global_load_lds(
        (const __attribute__((address_space(1))) void*)g,
        (__attribute__((address_space(3))) void*)l, 16, 0, 0);
}

// ---- pass 0: W (f32 [N][K]) -> bf16, chunk-XOR-swizzled (R2-proven) ----
// Wws[n][kt*64 + (ck^(n&7))*8 + j] = bf16(W[n][kt*64 + ck*8 + j])
__global__ __launch_bounds__(256)
void convert_W(const float* __restrict__ W, bf16_t* __restrict__ Wws)
{
    const int g  = blockIdx.x * 256 + threadIdx.x;
    const int n  = g >> 6;
    const int c  = g & 63;
    const int kt = c >> 3, ck = c & 7;
    const float4* src = reinterpret_cast<const float4*>(W + (size_t)n * K_TOT + c * 8);
    float4 v0 = src[0], v1 = src[1];
    bf16x8 b;
    b[0] = (bf16_t)v0.x; b[1] = (bf16_t)v0.y; b[2] = (bf16_t)v0.z; b[3] = (bf16_t)v0.w;
    b[4] = (bf16_t)v1.x; b[5] = (bf16_t)v1.y; b[6] = (bf16_t)v1.z; b[7] = (bf16_t)v1.w;
    *reinterpret_cast<bf16x8*>(Wws + (size_t)n * K_TOT + ((size_t)kt * 64 + ((ck ^ (n & 7)) * 8))) = b;
}

// ---- pass 1: Q = bf16(cos(x+phi)), written in the SAME swizzled layout ----
// chunk g (8 elems): row m = g>>6, c = g&63, kt=c>>3, ck=c&7.
// phi idx of elem kt*64+ck*8+j is j (ck*8 = 0 mod 8).
__global__ __launch_bounds__(256)
void qcos_pass(const float* __restrict__ x, const float* __restrict__ phi,
               bf16_t* __restrict__ Qws)
{
    float ph[8];
    #pragma unroll
    for (int j = 0; j < 8; ++j) ph[j] = phi[j];

    const size_t base = (size_t)blockIdx.x * 256 + threadIdx.x;
    #pragma unroll
    for (int it = 0; it < 4; ++it) {
        const size_t g = base + (size_t)it * 1048576;   // 4,194,304 chunks total
        const int m  = (int)(g >> 6);
        const int c  = (int)(g & 63);
        const int kt = c >> 3, ck = c & 7;
        const float4* s = reinterpret_cast<const float4*>(x + g * 8);
        float4 v0 = s[0], v1 = s[1];
        bf16x8 q;
        q[0] = (bf16_t)__cosf(v0.x + ph[0]); q[1] = (bf16_t)__cosf(v0.y + ph[1]);
        q[2] = (bf16_t)__cosf(v0.z + ph[2]); q[3] = (bf16_t)__cosf(v0.w + ph[3]);
        q[4] = (bf16_t)__cosf(v1.x + ph[4]); q[5] = (bf16_t)__cosf(v1.y + ph[5]);
        q[6] = (bf16_t)__cosf(v1.z + ph[6]); q[7] = (bf16_t)__cosf(v1.w + ph[7]);
        *reinterpret_cast<bf16x8*>(Qws + (size_t)m * K_TOT + kt * 64 + ((ck ^ (m & 7)) * 8)) = q;
    }
}

// ---- pass 2: pure bf16 GEMM out = Q @ W^T + bias (m97 structure) ----
__global__ __launch_bounds__(256, 3)
void gemm_qw(const bf16_t* __restrict__ Qws, const bf16_t* __restrict__ Wws,
             const float* __restrict__ bias, float* __restrict__ out)
{
    __shared__ bf16_t As[BM][BK];   // 16 KB swizzled image
    __shared__ bf16_t Bs[BN][BK];   // 16 KB swizzled image

    const int tid  = threadIdx.x;
    const int lane = tid & 63;
    const int wave = tid >> 6;

    // XCD-bijective swizzle (2048 % 8 == 0), bn-fastest: panel-sharers on one XCD.
    const int xcd = blockIdx.x & 7;
    const int idx = blockIdx.x >> 3;
    const int wid = xcd * 256 + idx;
    const int bm  = (wid >> 2) * BM;
    const int bn  = (wid & 3)  * BN;

    const int wm   = (wave >> 1) * 64;
    const int wn   = (wave & 1) * 64;
    const int frow = lane & 15;
    const int fk   = (lane >> 4) * 8;

    const int row8 = lane >> 3;     // staging: 8 rows per instr
    const int ck   = lane & 7;

    f32x4 acc[4][4] = {};

    for (int t = 0; t < NT; ++t) {
        // ---- stage A(t), B(t): 4+4 gload_lds per wave, linear dest ----
        #pragma unroll
        for (int i = 0; i < 4; ++i)
            gload_lds16(Qws + (size_t)(bm + wave * 32 + i * 8 + row8) * K_TOT + t * BK + ck * 8,
                        &As[0][0] + wave * 2048 + i * 512);
        #pragma unroll
        for (int i = 0; i < 4; ++i)
            gload_lds16(Wws + (size_t)(bn + wave * 32 + i * 8 + row8) * K_TOT + t * BK + ck * 8,
                        &Bs[0][0] + wave * 2048 + i * 512);
        asm volatile("s_waitcnt vmcnt(0) lgkmcnt(0)\n\ts_barrier" ::: "memory");

        // ---- fragments + 32 MFMA ----
        #pragma unroll
        for (int kk = 0; kk < 2; ++kk) {
            bf16x8 af[4], bfr[4];
            #pragma unroll
            for (int mi = 0; mi < 4; ++mi) {
                const int r = wm + mi * 16 + frow;
                af[mi] = *reinterpret_cast<bf16x8*>(&As[r][(kk * 32 + fk) ^ ((r & 7) << 3)]);
            }
            #pragma unroll
            for (int nj = 0; nj < 4; ++nj) {
                const int r = wn + nj * 16 + frow;
                bfr[nj] = *reinterpret_cast<bf16x8*>(&Bs[r][(kk * 32 + fk) ^ ((r & 7) << 3)]);
            }
            #pragma unroll
            for (int mi = 0; mi < 4; ++mi)
                #pragma unroll
                for (int nj = 0; nj < 4; ++nj)
                    acc[mi][nj] = __builtin_amdgcn_mfma_f32_16x16x32_bf16(
                        af[mi], bfr[nj], acc[mi][nj], 0, 0, 0);
        }

        // ---- release LDS for next stage ----
        if (t < NT - 1)
            asm volatile("s_waitcnt lgkmcnt(0)\n\ts_barrier" ::: "memory");
    }

    // ---- epilogue: C/D map col=lane&15, row=(lane>>4)*4+i ----
    #pragma unroll
    for (int nj = 0; nj < 4; ++nj) {
        const int c  = bn + wn + nj * 16 + frow;
        const float bv = bias[c];
        #pragma unroll
        for (int mi = 0; mi < 4; ++mi) {
            const int r0 = bm + wm + mi * 16 + (lane >> 4) * 4;
            #pragma unroll
            for (int i = 0; i < 4; ++i)
                out[(size_t)(r0 + i) * N_TOT + c] = acc[mi][nj][i] + bv;
        }
    }
}

// ---- fallback: R2/R4 fused champion, no-workspace variant ----
__global__ __launch_bounds__(256, 3)
void qattn_fused_fallback(const float* __restrict__ x, const float* __restrict__ phi,
                          const float* __restrict__ W, const float* __restrict__ bias,
                          float* __restrict__ out)
{
    __shared__ bf16_t As[BM][BK];
    __shared__ bf16_t Bs[BN][BK];

    const int tid  = threadIdx.x;
    const int lane = tid & 63;
    const int wave = tid >> 6;
    const int xcd = blockIdx.x & 7;
    const int idx = blockIdx.x >> 3;
    const int wid = xcd * 256 + idx;
    const int bm  = (wid >> 2) * BM;
    const int bn  = (wid & 3)  * BN;

    const int srow = tid >> 4;
    const int scol = (tid & 15) * 4;
    const int pbase = scol & 4;
    const float p0 = phi[pbase + 0], p1 = phi[pbase + 1];
    const float p2 = phi[pbase + 2], p3 = phi[pbase + 3];

    const int wm = (wave >> 1) * 64, wn = (wave & 1) * 64;
    const int frow = lane & 15, fk = (lane >> 4) * 8;

    f32x4 acc[4][4] = {};

    for (int k0 = 0; k0 < K_TOT; k0 += BK) {
        #pragma unroll
        for (int p = 0; p < 8; ++p) {
            const int row = srow + p * 16;
            const int csw = scol ^ ((row & 7) << 3);
            float4 v = *reinterpret_cast<const float4*>(x + (size_t)(bm + row) * K_TOT + k0 + scol);
            bf16x4 a;
            a[0] = (bf16_t)__cosf(v.x + p0); a[1] = (bf16_t)__cosf(v.y + p1);
            a[2] = (bf16_t)__cosf(v.z + p2); a[3] = (bf16_t)__cosf(v.w + p3);
            *reinterpret_cast<bf16x4*>(&As[row][csw]) = a;
            float4 w = *reinterpret_cast<const float4*>(W + (size_t)(bn + row) * K_TOT + k0 + scol);
            bf16x4 b;
            b[0] = (bf16_t)w.x; b[1] = (bf16_t)w.y; b[2] = (bf16_t)w.z; b[3] = (bf16_t)w.w;
            *reinterpret_cast<bf16x4*>(&Bs[row][csw]) = b;
        }
        __syncthreads();
        #pragma unroll
        for (int kk = 0; kk < 2; ++kk) {
            bf16x8 af[4], bfr[4];
            #pragma unroll
            for (int mi = 0; mi < 4; ++mi) {
                const int r = wm + mi * 16 + frow;
                af[mi] = *reinterpret_cast<bf16x8*>(&As[r][(kk * 32 + fk) ^ ((r & 7) << 3)]);
            }
            #pragma unroll
            for (int nj = 0; nj < 4; ++nj) {
                const int r = wn + nj * 16 + frow;
                bfr[nj] = *reinterpret_cast<bf16x8*>(&Bs[r][(kk * 32 + fk) ^ ((r & 7) << 3)]);
            }
            #pragma unroll
            for (int mi = 0; mi < 4; ++mi)
                #pragma unroll
                for (int nj = 0; nj < 4; ++nj)
                    acc[mi][nj] = __builtin_amdgcn_mfma_f32_16x16x32_bf16(
                        af[mi], bfr[nj], acc[mi][nj], 0, 0, 0);
        }
        __syncthreads();
    }
    #pragma unroll
    for (int nj = 0; nj < 4; ++nj) {
        const int c = bn + wn + nj * 16 + frow;
        const float bv = bias[c];
        #pragma unroll
        for (int mi = 0; mi < 4; ++mi) {
            const int r0 = bm + wm + mi * 16 + (lane >> 4) * 4;
            #pragma unroll
            for (int i = 0; i < 4; ++i)
                out[(size_t)(r0 + i) * N_TOT + c] = acc[mi][nj][i] + bv;
        }
    }
}

extern "C" void kernel_launch(void* const* d_in, const int* in_sizes, int n_in,
                              void* d_out, int out_size, void* d_ws, size_t ws_size,
                              hipStream_t stream) {
    const float* x    = (const float*)d_in[0];
    const float* phi  = (const float*)d_in[1];
    const float* W    = (const float*)d_in[2];
    const float* bias = (const float*)d_in[3];
    float* out = (float*)d_out;

    const size_t q_bytes = (size_t)M_TOT * K_TOT * sizeof(bf16_t);   // 64 MB
    const size_t w_bytes = (size_t)N_TOT * K_TOT * sizeof(bf16_t);   // 512 KB
    const int grid = (M_TOT / BM) * (N_TOT / BN);                    // 2048

    if (ws_size >= q_bytes + w_bytes) {
        bf16_t* Qws = (bf16_t*)d_ws;
        bf16_t* Wws = (bf16_t*)((char*)d_ws + q_bytes);
        convert_W<<<(N_TOT * K_TOT / 8) / 256, 256, 0, stream>>>(W, Wws);
        qcos_pass<<<4096, 256, 0, stream>>>(x, phi, Qws);
        gemm_qw<<<grid, 256, 0, stream>>>(Qws, Wws, bias, out);
    } else {
        qattn_fused_fallback<<<grid, 256, 0, stream>>>(x, phi, W, bias, out);
    }
}

// Round 10
// 85.426 us; speedup vs baseline: 1.8382x; 1.1137x over previous
//
#include <hip/hip_runtime.h>
#include <hip/hip_bf16.h>

typedef __bf16 bf16_t;
typedef bf16_t bf16x4 __attribute__((ext_vector_type(4)));
typedef bf16_t bf16x8 __attribute__((ext_vector_type(8)));
typedef float  f32x4  __attribute__((ext_vector_type(4)));

constexpr int M_TOT = 65536;   // B*S
constexpr int N_TOT = 512;     // E
constexpr int K_TOT = 512;     // E
constexpr int BM = 128, BN = 256, BK = 64;
constexpr int NT = K_TOT / BK; // 8 K-tiles

__device__ inline void gload_lds16(const void* g, void* l) {
    __builtin_amdgcn_global_load_lds(
        (const __attribute__((address_space(1))) void*)g,
        (__attribute__((address_space(3))) void*)l, 16, 0, 0);
}

// W (f32 [N][K]) -> bf16, chunk-XOR-swizzled: main kernel global_load_lds's it
// LINEARLY, reads back with chunk XOR. Wws[n][kt*64+(ck^(n&7))*8+j]=bf16(W[n][kt*64+ck*8+j])
__global__ __launch_bounds__(256)
void convert_W(const float* __restrict__ W, bf16_t* __restrict__ Wws)
{
    const int g  = blockIdx.x * 256 + threadIdx.x;
    const int n  = g >> 6;
    const int c  = g & 63;
    const int kt = c >> 3, ck = c & 7;
    const float4* src = reinterpret_cast<const float4*>(W + (size_t)n * K_TOT + c * 8);
    float4 v0 = src[0], v1 = src[1];
    bf16x8 b;
    b[0] = (bf16_t)v0.x; b[1] = (bf16_t)v0.y; b[2] = (bf16_t)v0.z; b[3] = (bf16_t)v0.w;
    b[4] = (bf16_t)v1.x; b[5] = (bf16_t)v1.y; b[6] = (bf16_t)v1.z; b[7] = (bf16_t)v1.w;
    const int dc = kt * 64 + ((ck ^ (n & 7)) * 8);
    *reinterpret_cast<bf16x8*>(Wws + (size_t)n * K_TOT + dc) = b;
}

// out[m,n] = sum_k cos(x[m,k] + phi[k%8]) * W[n,k] + bias[n]
// R10: 128x256 tile (BN=256) halves the #blocks -> halves TOTAL cos work
// (4x -> 2x recompute) and doubles MFMA payload per barrier period, keeping
// R6's verified 512-thread 2-barrier topology + counted vmcnt.
// (512,2): 256-reg budget, spill-proof (R3 lesson). LDS 48 KB.
template<bool USE_WS>
__global__ __launch_bounds__(512, 2)
void qattn_fused_gemm(const float* __restrict__ x,
                      const float* __restrict__ phi,
                      const float* __restrict__ W,
                      const bf16_t* __restrict__ Wws,
                      const float* __restrict__ bias,
                      float* __restrict__ out)
{
    __shared__ bf16_t As[BM][BK];   // 16 KB, XOR-swizzled
    __shared__ bf16_t Bs[BN][BK];   // 32 KB, XOR-swizzled image

    const int tid  = threadIdx.x;
    const int lane = tid & 63;
    const int wave = tid >> 6;      // 0..7

    // XCD-bijective swizzle (1024 blocks, 1024%8==0): wid = xcd*128 + idx,
    // bn-fastest -> the 2 blocks sharing an x-panel are consecutive on one XCD.
    const int xcd = blockIdx.x & 7;
    const int idx = blockIdx.x >> 3;
    const int wid = xcd * 128 + idx;
    const int bm  = (wid >> 1) * BM;   // 512 m-panels
    const int bn  = (wid & 1)  * BN;   // 2 n-panels

    // A staging: thread t -> row t>>2 (0..127), cols (t&3)*16 .. +15
    const int srow = tid >> 2;
    const int scol = (tid & 3) * 16;

    float ph[8];
    #pragma unroll
    for (int j = 0; j < 8; ++j) ph[j] = phi[j];

    // wave grid 4M x 2N: wave owns 32 rows x 128 cols of the 128x256 tile
    const int wm   = (wave >> 1) * 32;
    const int wn   = (wave & 1) * 128;
    const int frow = lane & 15;
    const int fk   = (lane >> 4) * 8;

    f32x4  acc[2][8] = {};     // 64 f32/thread
    float4 pa[4];              // x(t) in flight: 16 contiguous floats of row srow

    const float* xrow = x + (size_t)(bm + srow) * K_TOT + scol;

    // ---- prologue: B(0) first (oldest in vmcnt FIFO), then x(0) ----
    if constexpr (USE_WS) {
        #pragma unroll
        for (int i = 0; i < 4; ++i) {
            const bf16_t* src = Wws + (size_t)(bn + wave * 32 + i * 8 + (lane >> 3)) * K_TOT
                                + (lane & 7) * 8;
            gload_lds16(src, &Bs[0][0] + wave * 2048 + i * 512);
        }
        __builtin_amdgcn_sched_barrier(0);
    } else {
        const int brow = tid >> 1;
        #pragma unroll
        for (int i = 0; i < 4; ++i) {
            const int ck = (tid & 1) * 4 + i;
            const float4* s = reinterpret_cast<const float4*>(
                W + (size_t)(bn + brow) * K_TOT + ck * 8);
            float4 v0 = s[0], v1 = s[1];
            bf16x8 b;
            b[0] = (bf16_t)v0.x; b[1] = (bf16_t)v0.y; b[2] = (bf16_t)v0.z; b[3] = (bf16_t)v0.w;
            b[4] = (bf16_t)v1.x; b[5] = (bf16_t)v1.y; b[6] = (bf16_t)v1.z; b[7] = (bf16_t)v1.w;
            *reinterpret_cast<bf16x8*>(&Bs[brow][(ck ^ (brow & 7)) * 8]) = b;
        }
    }
    #pragma unroll
    for (int q = 0; q < 4; ++q)
        pa[q] = *reinterpret_cast<const float4*>(xrow + q * 4);

    #pragma unroll
    for (int t = 0; t < NT; ++t) {
        const bool last = (t == NT - 1);
        const int  kn   = (t + 1) * BK;

        // ---- A(t): cos from prefetched regs -> LDS (2x ds_write_b128) ----
        #pragma unroll
        for (int j = 0; j < 2; ++j) {
            bf16x8 a;
            #pragma unroll
            for (int q = 0; q < 2; ++q) {
                const float4 v = pa[j * 2 + q];
                a[q * 4 + 0] = (bf16_t)__cosf(v.x + ph[(q & 1) * 4 + 0]);
                a[q * 4 + 1] = (bf16_t)__cosf(v.y + ph[(q & 1) * 4 + 1]);
                a[q * 4 + 2] = (bf16_t)__cosf(v.z + ph[(q & 1) * 4 + 2]);
                a[q * 4 + 3] = (bf16_t)__cosf(v.w + ph[(q & 1) * 4 + 3]);
            }
            const int c = (scol + j * 8) ^ ((srow & 7) << 3);
            *reinterpret_cast<bf16x8*>(&As[srow][c]) = a;
        }

        // ---- issue x(t+1): the ONLY vmem newer than B(t) at SYNC1 ----
        if (!last) {
            #pragma unroll
            for (int q = 0; q < 4; ++q)
                pa[q] = *reinterpret_cast<const float4*>(xrow + kn + q * 4);
        }

        // ---- SYNC1: drain B(t)'s 4 gloads; 4 newer x-loads stay in flight ----
        if (USE_WS) {
            if (!last) asm volatile("s_waitcnt vmcnt(4) lgkmcnt(0)\n\ts_barrier" ::: "memory");
            else       asm volatile("s_waitcnt vmcnt(0) lgkmcnt(0)\n\ts_barrier" ::: "memory");
        } else {
            asm volatile("s_waitcnt lgkmcnt(0)\n\ts_barrier" ::: "memory");
        }

        // ---- compute: 4 af + 16 bfr ds_reads, 32 MFMAs/wave ----
        #pragma unroll
        for (int kk = 0; kk < 2; ++kk) {
            bf16x8 af[2], bfr[8];
            #pragma unroll
            for (int mi = 0; mi < 2; ++mi) {
                const int r = wm + mi * 16 + frow;
                const int c = (kk * 32 + fk) ^ ((r & 7) << 3);
                af[mi] = *reinterpret_cast<bf16x8*>(&As[r][c]);
            }
            #pragma unroll
            for (int nj = 0; nj < 8; ++nj) {
                const int r = wn + nj * 16 + frow;
                const int c = (kk * 32 + fk) ^ ((r & 7) << 3);
                bfr[nj] = *reinterpret_cast<bf16x8*>(&Bs[r][c]);
            }
            __builtin_amdgcn_s_setprio(1);
            #pragma unroll
            for (int mi = 0; mi < 2; ++mi)
                #pragma unroll
                for (int nj = 0; nj < 8; ++nj)
                    acc[mi][nj] = __builtin_amdgcn_mfma_f32_16x16x32_bf16(
                        af[mi], bfr[nj], acc[mi][nj], 0, 0, 0);
            __builtin_amdgcn_s_setprio(0);
        }

        // ---- SYNC2 + stage B(t+1) (overwrites Bs -> must follow SYNC2) ----
        if (!last) {
            asm volatile("s_waitcnt lgkmcnt(0)\n\ts_barrier" ::: "memory");
            if constexpr (USE_WS) {
                #pragma unroll
                for (int i = 0; i < 4; ++i) {
                    const bf16_t* src = Wws
                        + (size_t)(bn + wave * 32 + i * 8 + (lane >> 3)) * K_TOT
                        + kn + (lane & 7) * 8;
                    gload_lds16(src, &Bs[0][0] + wave * 2048 + i * 512);
                }
                __builtin_amdgcn_sched_barrier(0);
            } else {
                const int brow = tid >> 1;
                #pragma unroll
                for (int i = 0; i < 4; ++i) {
                    const int ck = (tid & 1) * 4 + i;
                    const float4* s = reinterpret_cast<const float4*>(
                        W + (size_t)(bn + brow) * K_TOT + kn + ck * 8);
                    float4 v0 = s[0], v1 = s[1];
                    bf16x8 b;
                    b[0] = (bf16_t)v0.x; b[1] = (bf16_t)v0.y; b[2] = (bf16_t)v0.z; b[3] = (bf16_t)v0.w;
                    b[4] = (bf16_t)v1.x; b[5] = (bf16_t)v1.y; b[6] = (bf16_t)v1.z; b[7] = (bf16_t)v1.w;
                    *reinterpret_cast<bf16x8*>(&Bs[brow][(ck ^ (brow & 7)) * 8]) = b;
                }
            }
        }
    }

    // ---- epilogue: C/D map col=lane&15, row=(lane>>4)*4+i ----
    #pragma unroll
    for (int nj = 0; nj < 8; ++nj) {
        const int c  = bn + wn + nj * 16 + frow;
        const float bv = bias[c];
        #pragma unroll
        for (int mi = 0; mi < 2; ++mi) {
            const int r0 = bm + wm + mi * 16 + (lane >> 4) * 4;
            #pragma unroll
            for (int i = 0; i < 4; ++i)
                out[(size_t)(r0 + i) * N_TOT + c] = acc[mi][nj][i] + bv;
        }
    }
}

extern "C" void kernel_launch(void* const* d_in, const int* in_sizes, int n_in,
                              void* d_out, int out_size, void* d_ws, size_t ws_size,
                              hipStream_t stream) {
    const float* x    = (const float*)d_in[0];
    const float* phi  = (const float*)d_in[1];
    const float* W    = (const float*)d_in[2];
    const float* bias = (const float*)d_in[3];
    float* out = (float*)d_out;

    const int grid = (M_TOT / BM) * (N_TOT / BN);   // 1024
    const size_t ws_need = (size_t)N_TOT * K_TOT * sizeof(bf16_t);  // 512 KB

    if (ws_size >= ws_need) {
        bf16_t* Wws = (bf16_t*)d_ws;
        convert_W<<<(N_TOT * K_TOT / 8) / 256, 256, 0, stream>>>(W, Wws);
        qattn_fused_gemm<true><<<grid, 512, 0, stream>>>(x, phi, W, Wws, bias, out);
    } else {
        qattn_fused_gemm<false><<<grid, 512, 0, stream>>>(x, phi, W, nullptr, bias, out);
    }
}